// Round 1
// 735.559 us; speedup vs baseline: 1.0211x; 1.0211x over previous
//
#include <hip/hip_runtime.h>
#include <cstdint>
#include <cstddef>

#define TT 2048
#define DD 1024
#define FF 2048
#define NG 16
#define PSLOT 10240
#define EPSV 1e-5f

typedef __attribute__((ext_vector_type(8))) short short8;
typedef __attribute__((ext_vector_type(4))) float floatx4;

__device__ inline unsigned short f2bf(float f) {
  union { float f; unsigned int u; } v; v.f = f;
  unsigned int r = v.u + 0x7fffu + ((v.u >> 16) & 1u);
  return (unsigned short)(r >> 16);
}

__device__ __forceinline__ void gl2lds(const void* g, void* l) {
  __builtin_amdgcn_global_load_lds(
      (const __attribute__((address_space(1))) void*)g,
      (__attribute__((address_space(3))) void*)l, 16, 0, 0);
}

// Packed bf16 layout: [K/32][N][32], with the 16B granule of each 64B row
// XOR-swizzled by row bits 1..2:  u16pos = (k&31) ^ (((row>>1)&3)<<3).
// global_load_lds copies rows linearly; ds_read applies the same XOR ->
// each 8-lane LDS phase hits all 8 bank groups (conflict-free).

// ---------------- routing ----------------
__global__ __launch_bounds__(256) void k_route(
    const float* __restrict__ xf, const float* __restrict__ Wrc,
    const float* __restrict__ brc, const float* __restrict__ Wre,
    const float* __restrict__ bre, float* __restrict__ gate,
    float* __restrict__ coefs, float* __restrict__ tstats,
    int* __restrict__ counts)
{
  int t = blockIdx.x;
  const float* xr = xf + (size_t)t * DD;
  float v[22];
#pragma unroll
  for (int i = 0; i < 22; i++) v[i] = 0.f;
  for (int d = threadIdx.x; d < DD; d += 256) {
    float x = xr[d];
    v[20] += x; v[21] += x * x;
    float4 wc = *(const float4*)(Wrc + (size_t)d * 4);
    v[0] += x * wc.x; v[1] += x * wc.y; v[2] += x * wc.z; v[3] += x * wc.w;
#pragma unroll
    for (int c = 0; c < 4; c++) {
      float4 we = *(const float4*)(Wre + ((size_t)c * DD + d) * 4);
      v[4 + c*4 + 0] += x * we.x; v[4 + c*4 + 1] += x * we.y;
      v[4 + c*4 + 2] += x * we.z; v[4 + c*4 + 3] += x * we.w;
    }
  }
#pragma unroll
  for (int m = 32; m >= 1; m >>= 1)
#pragma unroll
    for (int i = 0; i < 22; i++) v[i] += __shfl_xor(v[i], m);
  __shared__ float red[4][22];
  int wave = threadIdx.x >> 6, lane = threadIdx.x & 63;
  if (lane == 0) for (int i = 0; i < 22; i++) red[wave][i] = v[i];
  __syncthreads();
  if (threadIdx.x == 0) {
    for (int i = 0; i < 22; i++) v[i] = red[0][i] + red[1][i] + red[2][i] + red[3][i];
    float mean = v[20] / DD;
    float var  = v[21] / DD - mean * mean;
    tstats[t*2]   = mean;
    tstats[t*2+1] = rsqrtf(var + EPSV);
    float p[4]; float mx = -1e30f;
    for (int c = 0; c < 4; c++) { v[c] += brc[c]; mx = fmaxf(mx, v[c]); }
    for (int c = 0; c < 4; c++) p[c] = expf(v[c] - mx);
    int c0 = 0;
    for (int c = 1; c < 4; c++) if (p[c] > p[c0]) c0 = c;
    int c1 = (c0 == 0) ? 1 : 0;
    for (int c = 0; c < 4; c++) if (c != c0 && p[c] > p[c1]) c1 = c;
    float ws = p[c0] + p[c1];
    gate[t*4 + c0] = p[c0] / ws;
    gate[t*4 + c1] = p[c1] / ws;
    int sels[2] = {c0, c1};
    for (int si = 0; si < 2; si++) {
      int c = sels[si];
      float l[4];
      for (int e = 0; e < 4; e++) l[e] = v[4 + c*4 + e] + bre[c*4 + e];
      int e0 = 0;
      for (int e = 1; e < 4; e++) if (l[e] > l[e0]) e0 = e;
      int e1 = (e0 == 0) ? 1 : 0;
      for (int e = 0; e < 4; e++) if (e != e0 && l[e] > l[e1]) e1 = e;
      float q1 = expf(l[e1] - l[e0]);
      float r0 = 1.f / (1.f + q1);
      float r1 = q1 / (1.f + q1);
      if (r0 > 0.f) { coefs[t*16 + c*4 + e0] = r0; atomicAdd(&counts[c*4 + e0], 1); }
      if (r1 > 0.f) { coefs[t*16 + c*4 + e1] = r1; atomicAdd(&counts[c*4 + e1], 1); }
    }
  }
}

__global__ void k_offsets(const int* __restrict__ counts, int* __restrict__ poffs) {
  if (threadIdx.x == 0 && blockIdx.x == 0) {
    int s = 0;
    for (int i = 0; i < NG; i++) { poffs[i] = s; s += (counts[i] + 127) & ~127; }
    poffs[NG] = s;
  }
}

__global__ __launch_bounds__(256) void k_fill(
    const float* __restrict__ coefs, const int* __restrict__ poffs,
    int* __restrict__ cursor, int* __restrict__ slot_token, int* __restrict__ inv_slot)
{
  int idx = blockIdx.x * 256 + threadIdx.x;
  if (idx >= TT * NG) return;
  int t = idx >> 4, ce = idx & 15;
  if (coefs[idx] > 0.f) {
    int pos = atomicAdd(&cursor[ce], 1);
    int s = poffs[ce] + pos;
    slot_token[s] = t;
    inv_slot[idx] = s;
  }
}

// ---------------- weight pack: [K][N] fp32 -> [K/32][NV][32] bf16 (swizzled) ----
// mode 0: gs=gd, v=n           (plain)
// mode 1: gs=single-expert(gd), v=n        (W1 for gelu/relu groups)
// mode 2: gs=dual-expert(gd),  v=(n>>6)*128+(n&63)      (W1 half of W12)
// mode 3: gs=dual-expert(gd),  v=(n>>6)*128+64+(n&63)   (W2 half of W12)
__global__ __launch_bounds__(256) void k_pack(
    const float* __restrict__ src, unsigned short* __restrict__ dst,
    int K, int N, int NV, int mode)
{
  int gd = blockIdx.z;
  int gs;
  if (mode == 0) gs = gd;
  else if (mode == 1) gs = (gd >> 1) * 4 + 1 + (gd & 1);
  else gs = (gd >> 1) * 4 + ((gd & 1) ? 3 : 0);
  const float* S = src + (size_t)gs * K * N;
  unsigned short* D = dst + (size_t)gd * K * NV;
  int k0 = blockIdx.y * 64, nb = blockIdx.x * 64;
  int vb = (mode >= 2) ? ((nb >> 6) * 128 + ((mode == 3) ? 64 : 0)) : nb;
  __shared__ float T[64][65];
  int r0 = threadIdx.x >> 4, c4 = (threadIdx.x & 15) * 4;
#pragma unroll
  for (int r = 0; r < 4; r++) {
    int row = r0 + 16 * r;
    float4 v = *(const float4*)(S + (size_t)(k0 + row) * N + nb + c4);
    T[row][c4] = v.x; T[row][c4+1] = v.y; T[row][c4+2] = v.z; T[row][c4+3] = v.w;
  }
  __syncthreads();
#pragma unroll
  for (int r = 0; r < 4; r++) {
    int nrow = r0 + 16 * r;
    int vrow = vb + nrow;
    ushort4 o;
    o.x = f2bf(T[c4+0][nrow]); o.y = f2bf(T[c4+1][nrow]);
    o.z = f2bf(T[c4+2][nrow]); o.w = f2bf(T[c4+3][nrow]);
    size_t off = (size_t)((k0 + c4) >> 5) * ((size_t)NV * 32)
               + (size_t)vrow * 32 + (size_t)((c4 & 31) ^ (((vrow >> 1) & 3) << 3));
    *(ushort4*)(D + off) = o;
  }
}

// ---------------- gather + LN_in -> packed bf16 [DD/32][PSLOT][32] (swizzled) ---
__global__ __launch_bounds__(256) void k_gather(
    const float* __restrict__ xf, const float* __restrict__ tstats,
    const float* __restrict__ lin_g, const float* __restrict__ lin_b,
    const int* __restrict__ poffs, const int* __restrict__ counts,
    const int* __restrict__ slot_token, unsigned short* __restrict__ Xgp)
{
  int s = blockIdx.x;
  int g = 0;
  while (g < NG - 1 && s >= poffs[g + 1]) g++;
  if (s - poffs[g] >= counts[g]) return;
  int t = slot_token[s];
  float mean = tstats[t*2], rstd = tstats[t*2+1];
  int d = threadIdx.x * 4;
  float4 x  = *(const float4*)(xf + (size_t)t*DD + d);
  float4 gg = *(const float4*)(lin_g + (size_t)g*DD + d);
  float4 bb = *(const float4*)(lin_b + (size_t)g*DD + d);
  ushort4 o;
  o.x = f2bf((x.x - mean)*rstd*gg.x + bb.x);
  o.y = f2bf((x.y - mean)*rstd*gg.y + bb.y);
  o.z = f2bf((x.z - mean)*rstd*gg.z + bb.z);
  o.w = f2bf((x.w - mean)*rstd*gg.w + bb.w);
  *(ushort4*)(Xgp + (size_t)(d >> 5) * (PSLOT * 32) + (size_t)s * 32
              + (size_t)((d & 31) ^ (((s >> 1) & 3) << 3))) = o;
}

// ---------------- GEMM1: 3-stage BK=32 pipeline, counted vmcnt, swizzled LDS ----
// dual groups (e in {0,3}): B tile = [64 W1-cols | 64 W2-cols], 32 n-tiles
// single groups (e in {1,2}): B tile = 128 W1-cols, 16 n-tiles
__global__ __launch_bounds__(256, 3) void k_gemm1(
    const unsigned short* __restrict__ Xgp, const unsigned short* __restrict__ W1sp,
    const unsigned short* __restrict__ W12p, const int* __restrict__ counts,
    const int* __restrict__ poffs, unsigned short* __restrict__ Hp)
{
  int g = blockIdx.z;
  int e = g & 3, c = g >> 2;
  bool dual = (e == 0 || e == 3);
  int nt = blockIdx.x;
  if (!dual && nt >= 16) return;
  int count = counts[g];
  int M0 = blockIdx.y * 128;
  if (M0 >= count) return;
  int slot0 = poffs[g] + M0;

  __shared__ char smem[49152];   // 3 stages x (A 8KB + B 8KB)

  const char* Ab = (const char*)(Xgp + (size_t)slot0 * 32);
  const char* Bb;
  size_t bslab;
  if (dual) {
    int d2 = c * 2 + (e ? 1 : 0);
    Bb = (const char*)(W12p + (size_t)d2 * DD * (2 * FF) + (size_t)nt * 128 * 32);
    bslab = (size_t)(2 * FF) * 64;
  } else {
    int s2 = c * 2 + (e - 1);
    Bb = (const char*)(W1sp + (size_t)s2 * DD * FF + (size_t)nt * 128 * 32);
    bslab = (size_t)FF * 64;
  }
  const size_t aslab = (size_t)PSLOT * 64;

  int tid = threadIdx.x, lane = tid & 63, wv = tid >> 6;
  int m16 = lane & 15, quad = lane >> 4;
  int wrow = (wv >> 1) * 64, wcol = (wv & 1) * 64;
  int lo = lane * 16;
  int xq = ((quad ^ ((m16 >> 1) & 3)) << 4);   // swizzled 16B-granule offset

  floatx4 zero4 = {0.f, 0.f, 0.f, 0.f};
  floatx4 acc[4][4];
#pragma unroll
  for (int i = 0; i < 4; i++)
#pragma unroll
    for (int j = 0; j < 4; j++) acc[i][j] = zero4;

  // stage one 32-k chunk (A 8KB + B 8KB): 4x 1KB gl2lds per wave
  auto STAGE = [&](int kc) {
    char* L = smem + (kc % 3) * 16384;
    if (wv < 2) {
      const char* s = Ab + (size_t)kc * aslab + wv * 4096 + lo;
      char* d = L + wv * 4096;
      gl2lds(s,        d);
      gl2lds(s + 1024, d + 1024);
      gl2lds(s + 2048, d + 2048);
      gl2lds(s + 3072, d + 3072);
    } else {
      const char* s = Bb + (size_t)kc * bslab + (wv - 2) * 4096 + lo;
      char* d = L + 8192 + (wv - 2) * 4096;
      gl2lds(s,        d);
      gl2lds(s + 1024, d + 1024);
      gl2lds(s + 2048, d + 2048);
      gl2lds(s + 3072, d + 3072);
    }
  };

  STAGE(0); STAGE(1);
  for (int kc = 0; kc < 32; ++kc) {
    if (kc + 2 < 32) {
      STAGE(kc + 2);
      asm volatile("s_waitcnt vmcnt(8)" ::: "memory");   // 2 newer stages in flight
    } else if (kc + 1 < 32) {
      asm volatile("s_waitcnt vmcnt(4)" ::: "memory");
    } else {
      asm volatile("s_waitcnt vmcnt(0)" ::: "memory");
    }
    __builtin_amdgcn_s_barrier();
    __builtin_amdgcn_sched_barrier(0);
    const char* Al = smem + (kc % 3) * 16384;
    const char* Blc = Al + 8192;
    short8 af[4], bv[4];
#pragma unroll
    for (int mi = 0; mi < 4; mi++)
      af[mi] = *(const short8*)(Al + (wrow + mi*16 + m16) * 64 + xq);
#pragma unroll
    for (int ni = 0; ni < 4; ni++)
      bv[ni] = *(const short8*)(Blc + (wcol + ni*16 + m16) * 64 + xq);
#pragma unroll
    for (int mi = 0; mi < 4; mi++)
#pragma unroll
      for (int ni = 0; ni < 4; ni++)
        acc[mi][ni] = __builtin_amdgcn_mfma_f32_16x16x32_bf16(af[mi], bv[ni], acc[mi][ni], 0, 0, 0);
    __builtin_amdgcn_s_barrier();
  }

  if (dual) {
    float* ex = (float*)smem;  // [128][64] fp32 = 32 KB (stages dead)
    if (wv & 1) {  // h2 (W2) waves
#pragma unroll
      for (int mi = 0; mi < 4; mi++)
#pragma unroll
        for (int ni = 0; ni < 4; ni++)
#pragma unroll
          for (int r = 0; r < 4; r++) {
            int row = wrow + mi*16 + quad*4 + r;
            ex[row * 64 + ni*16 + m16] = acc[mi][ni][r];
          }
    }
    __syncthreads();
    if (!(wv & 1)) {  // h1 (W1) waves
#pragma unroll
      for (int mi = 0; mi < 4; mi++)
#pragma unroll
        for (int ni = 0; ni < 4; ni++)
#pragma unroll
          for (int r = 0; r < 4; r++) {
            int row = wrow + mi*16 + quad*4 + r;
            if (M0 + row < count) {
              int cl = ni*16 + m16;
              float h1 = acc[mi][ni][r];
              float h2 = ex[row * 64 + cl];
              float sil = h2 / (1.f + expf(-h2));
              float h = sil * h2 * h1;
              int col = nt * 64 + cl;
              int sl = slot0 + row;
              Hp[(size_t)(col >> 5) * (PSLOT * 32) + (size_t)sl * 32
                 + (size_t)((col & 31) ^ (((sl >> 1) & 3) << 3))] = f2bf(h);
            }
          }
    }
  } else {
#pragma unroll
    for (int mi = 0; mi < 4; mi++)
#pragma unroll
      for (int ni = 0; ni < 4; ni++)
#pragma unroll
        for (int r = 0; r < 4; r++) {
          int row = wrow + mi*16 + quad*4 + r;
          if (M0 + row < count) {
            int col = nt * 128 + wcol + ni*16 + m16;
            float h1 = acc[mi][ni][r];
            float h;
            if (e == 1) h = 0.5f * h1 * (1.f + erff(h1 * 0.70710678118f));
            else        h = fmaxf(h1, 0.f);
            int sl = slot0 + row;
            Hp[(size_t)(col >> 5) * (PSLOT * 32) + (size_t)sl * 32
               + (size_t)((col & 31) ^ (((sl >> 1) & 3) << 3))] = f2bf(h);
          }
        }
  }
}

// ---------------- GEMM2: Hp @ W3p -> Y, 3-stage BK=32 pipeline, swizzled --------
__global__ __launch_bounds__(256, 4) void k_gemm2(
    const unsigned short* __restrict__ Hp, const unsigned short* __restrict__ W3p,
    const int* __restrict__ counts, const int* __restrict__ poffs,
    float* __restrict__ Y)
{
  int g = blockIdx.z;
  int count = counts[g];
  int M0 = blockIdx.y * 128;
  if (M0 >= count) return;
  int nt = blockIdx.x;  // 0..15 (64 cols each)
  int slot0 = poffs[g] + M0;
  __shared__ char smem[36864];   // 3 stages x (A 8KB + B 4KB)
  const char* Ab = (const char*)(Hp + (size_t)slot0 * 32);
  const char* Bb = (const char*)(W3p + (size_t)g * FF * DD + (size_t)nt * 64 * 32);
  const size_t aslab = (size_t)PSLOT * 64;
  const size_t bslab = (size_t)DD * 64;
  int tid = threadIdx.x, lane = tid & 63, wv = tid >> 6;
  int m16 = lane & 15, quad = lane >> 4;
  int wrow = (wv >> 1) * 64, wcol = (wv & 1) * 32;
  int lo = lane * 16;
  int xq = ((quad ^ ((m16 >> 1) & 3)) << 4);
  floatx4 zero4 = {0.f, 0.f, 0.f, 0.f};
  floatx4 acc[4][2];
#pragma unroll
  for (int i = 0; i < 4; i++) { acc[i][0] = zero4; acc[i][1] = zero4; }

  // stage one 32-k chunk (A 8KB @ +0, B 4KB @ +8192): 3x 1KB gl2lds per wave
  auto STAGE = [&](int kc) {
    char* L = smem + (kc % 3) * 12288;
    const char* As = Ab + (size_t)kc * aslab;
    const char* Bs = Bb + (size_t)kc * bslab;
#pragma unroll
    for (int i = 0; i < 3; i++) {
      int o = wv * 3072 + i * 1024;
      const char* s = (o < 8192) ? (As + o) : (Bs + (o - 8192));
      gl2lds(s + lo, L + o);
    }
  };

  STAGE(0); STAGE(1);
  for (int kc = 0; kc < 64; ++kc) {
    if (kc + 2 < 64) {
      STAGE(kc + 2);
      asm volatile("s_waitcnt vmcnt(6)" ::: "memory");
    } else if (kc + 1 < 64) {
      asm volatile("s_waitcnt vmcnt(3)" ::: "memory");
    } else {
      asm volatile("s_waitcnt vmcnt(0)" ::: "memory");
    }
    __builtin_amdgcn_s_barrier();
    __builtin_amdgcn_sched_barrier(0);
    const char* Al = smem + (kc % 3) * 12288;
    const char* Blc = Al + 8192;
    short8 af[4], bv[2];
#pragma unroll
    for (int mi = 0; mi < 4; mi++)
      af[mi] = *(const short8*)(Al + (wrow + mi*16 + m16) * 64 + xq);
#pragma unroll
    for (int ni = 0; ni < 2; ni++)
      bv[ni] = *(const short8*)(Blc + (wcol + ni*16 + m16) * 64 + xq);
#pragma unroll
    for (int mi = 0; mi < 4; mi++)
#pragma unroll
      for (int ni = 0; ni < 2; ni++)
        acc[mi][ni] = __builtin_amdgcn_mfma_f32_16x16x32_bf16(af[mi], bv[ni], acc[mi][ni], 0, 0, 0);
    __builtin_amdgcn_s_barrier();
  }
#pragma unroll
  for (int mi = 0; mi < 4; mi++)
#pragma unroll
    for (int ni = 0; ni < 2; ni++)
#pragma unroll
      for (int r = 0; r < 4; r++) {
        int row = wrow + mi*16 + quad*4 + r;
        if (M0 + row < count)
          Y[(size_t)(slot0 + row) * DD + nt*64 + wcol + ni*16 + m16] = acc[mi][ni][r];
      }
}

// ---------------- per-slot LN_out stats ----------------
__global__ __launch_bounds__(256) void k_slotstats(
    const float* __restrict__ xf, const float* __restrict__ Y,
    const int* __restrict__ poffs, const int* __restrict__ counts,
    const int* __restrict__ slot_token, float* __restrict__ sstats)
{
  int s = blockIdx.x;
  int g = 0;
  while (g < NG - 1 && s >= poffs[g + 1]) g++;
  if (s - poffs[g] >= counts[g]) return;
  int t = slot_token[s];
  int d = threadIdx.x * 4;
  float4 yv = *(const float4*)(Y + (size_t)s*DD + d);
  float4 xv = *(const float4*)(xf + (size_t)t*DD + d);
  float z0 = xv.x + yv.x, z1 = xv.y + yv.y, z2 = xv.z + yv.z, z3 = xv.w + yv.w;
  float s1 = z0 + z1 + z2 + z3;
  float s2 = z0*z0 + z1*z1 + z2*z2 + z3*z3;
#pragma unroll
  for (int m = 32; m >= 1; m >>= 1) { s1 += __shfl_xor(s1, m); s2 += __shfl_xor(s2, m); }
  __shared__ float red[8];
  int wave = threadIdx.x >> 6, lane = threadIdx.x & 63;
  if (lane == 0) { red[wave*2] = s1; red[wave*2 + 1] = s2; }
  __syncthreads();
  if (threadIdx.x == 0) {
    float a = red[0] + red[2] + red[4] + red[6];
    float b = red[1] + red[3] + red[5] + red[7];
    float mean = a / DD;
    float var  = b / DD - mean * mean;
    sstats[s*2]   = mean;
    sstats[s*2+1] = rsqrtf(var + EPSV);
  }
}

// ---------------- final combine ----------------
__global__ __launch_bounds__(256) void k_final(
    const float* __restrict__ xf, const float* __restrict__ Y,
    const float* __restrict__ sstats, const int* __restrict__ inv_slot,
    const float* __restrict__ gate, const float* __restrict__ coefs,
    const float* __restrict__ lout_g, const float* __restrict__ lout_b,
    const float* __restrict__ cln_g, const float* __restrict__ cln_b,
    float* __restrict__ out)
{
  int t = blockIdx.x;
  int d = threadIdx.x * 4;
  int wave = threadIdx.x >> 6, lane = threadIdx.x & 63;
  float4 xv = *(const float4*)(xf + (size_t)t*DD + d);
  float4 o = {0.f, 0.f, 0.f, 0.f};
  __shared__ float red[8];
  for (int c = 0; c < 4; c++) {
    float gt = gate[t*4 + c];
    if (gt == 0.f) continue;
    float a0 = 0.f, a1 = 0.f, a2 = 0.f, a3 = 0.f;
    for (int e = 0; e < 4; e++) {
      float cf = coefs[t*16 + c*4 + e];
      if (cf <= 0.f) continue;
      int g = c*4 + e;
      int s = inv_slot[t*16 + g];
      float4 yv = *(const float4*)(Y + (size_t)s*DD + d);
      float mean = sstats[s*2], rstd = sstats[s*2+1];
      float4 gg = *(const float4*)(lout_g + (size_t)g*DD + d);
      float4 bb = *(const float4*)(lout_b + (size_t)g*DD + d);
      a0 += cf * ((xv.x + yv.x - mean)*rstd*gg.x + bb.x);
      a1 += cf * ((xv.y + yv.y - mean)*rstd*gg.y + bb.y);
      a2 += cf * ((xv.z + yv.z - mean)*rstd*gg.z + bb.z);
      a3 += cf * ((xv.w + yv.w - mean)*rstd*gg.w + bb.w);
    }
    float s1 = a0 + a1 + a2 + a3;
    float s2 = a0*a0 + a1*a1 + a2*a2 + a3*a3;
#pragma unroll
    for (int m = 32; m >= 1; m >>= 1) { s1 += __shfl_xor(s1, m); s2 += __shfl_xor(s2, m); }
    if (lane == 0) { red[wave*2] = s1; red[wave*2 + 1] = s2; }
    __syncthreads();
    float ts1 = red[0] + red[2] + red[4] + red[6];
    float ts2 = red[1] + red[3] + red[5] + red[7];
    __syncthreads();
    float mean = ts1 / DD;
    float rstd = rsqrtf(ts2 / DD - mean*mean + EPSV);
    float4 cg = *(const float4*)(cln_g + (size_t)c*DD + d);
    float4 cb = *(const float4*)(cln_b + (size_t)c*DD + d);
    o.x += gt * ((a0 - mean)*rstd*cg.x + cb.x);
    o.y += gt * ((a1 - mean)*rstd*cg.y + cb.y);
    o.z += gt * ((a2 - mean)*rstd*cg.z + cb.z);
    o.w += gt * ((a3 - mean)*rstd*cg.w + cb.w);
  }
  *(float4*)(out + (size_t)t*DD + d) = o;
}

extern "C" void kernel_launch(void* const* d_in, const int* in_sizes, int n_in,
                              void* d_out, int out_size, void* d_ws, size_t ws_size,
                              hipStream_t stream) {
  (void)in_sizes; (void)n_in; (void)out_size; (void)ws_size;
  const float* x      = (const float*)d_in[0];
  const float* W1     = (const float*)d_in[1];
  const float* W2     = (const float*)d_in[2];
  const float* W3     = (const float*)d_in[3];
  const float* lin_g  = (const float*)d_in[4];
  const float* lin_b  = (const float*)d_in[5];
  const float* lout_g = (const float*)d_in[6];
  const float* lout_b = (const float*)d_in[7];
  const float* cln_g  = (const float*)d_in[8];
  const float* cln_b  = (const float*)d_in[9];
  const float* Wrc    = (const float*)d_in[10];
  const float* brc    = (const float*)d_in[11];
  const float* Wre    = (const float*)d_in[12];
  const float* bre    = (const float*)d_in[13];
  float* out = (float*)d_out;
  char* ws = (char*)d_ws;

  int*   counts     = (int*)(ws + 0);
  int*   cursor     = (int*)(ws + 64);
  int*   poffs      = (int*)(ws + 128);
  float* gate       = (float*)(ws + 256);
  float* coefs      = (float*)(ws + 33024);
  float* tstats     = (float*)(ws + 164096);
  int*   slot_token = (int*)(ws + 180480);
  int*   inv_slot   = (int*)(ws + 221440);
  float* sstats     = (float*)(ws + 352512);
  unsigned short* Xgp  = (unsigned short*)(ws + 1048576);    // 20 MiB [DD/32][PSLOT][32]
  unsigned short* Hp   = (unsigned short*)(ws + 22020096);   // 40 MiB [FF/32][PSLOT][32]
  unsigned short* W1sp = (unsigned short*)(ws + 63963136);   // 32 MiB, 8 single groups
  unsigned short* W12p = (unsigned short*)(ws + 97517568);   // 64 MiB, 8 dual groups interleaved
  float*          Y    = (float*)(ws + 97517568);            // aliases W12p (dead after gemm1)
  unsigned short* W3p  = (unsigned short*)(ws + 164626432);  // 64 MiB, 16 groups
  // total ~221 MiB

  hipMemsetAsync(ws, 0, 256, stream);
  hipMemsetAsync(ws + 256, 0, 163840, stream);

  k_pack<<<dim3(FF/64, DD/64,  8), 256, 0, stream>>>(W1, W1sp, DD, FF, FF,     1);
  k_pack<<<dim3(FF/64, DD/64,  8), 256, 0, stream>>>(W1, W12p, DD, FF, 2*FF,   2);
  k_pack<<<dim3(FF/64, DD/64,  8), 256, 0, stream>>>(W2, W12p, DD, FF, 2*FF,   3);
  k_pack<<<dim3(DD/64, FF/64, 16), 256, 0, stream>>>(W3, W3p,  FF, DD, DD,     0);

  k_route<<<TT, 256, 0, stream>>>(x, Wrc, brc, Wre, bre, gate, coefs, tstats, counts);
  k_offsets<<<1, 64, 0, stream>>>(counts, poffs);
  k_fill<<<(TT*NG)/256, 256, 0, stream>>>(coefs, poffs, cursor, slot_token, inv_slot);
  k_gather<<<PSLOT, 256, 0, stream>>>(x, tstats, lin_g, lin_b, poffs, counts, slot_token, Xgp);
  k_gemm1<<<dim3(32, 16, 16), 256, 0, stream>>>(Xgp, W1sp, W12p, counts, poffs, Hp);
  k_gemm2<<<dim3(16, 16, 16), 256, 0, stream>>>(Hp, W3p, counts, poffs, Y);
  k_slotstats<<<PSLOT, 256, 0, stream>>>(x, Y, poffs, counts, slot_token, sstats);
  k_final<<<TT, 256, 0, stream>>>(x, Y, sstats, inv_slot, gate, coefs,
                                  lout_g, lout_b, cln_g, cln_b, out);
}